// Round 12
// baseline (92.116 us; speedup 1.0000x reference)
//
#include <hip/hip_runtime.h>
#include <math.h>

#define B_    4
#define CIN_  64
#define COUT_ 64
#define N_    32768
#define S_    8192

typedef __attribute__((ext_vector_type(8))) short short8;
typedef __attribute__((ext_vector_type(4))) float f32x4a;

static __device__ __forceinline__ unsigned short f2bf(float x) {
    unsigned u = __float_as_uint(x);
    u += 0x7fffu + ((u >> 16) & 1u);
    return (unsigned short)(u >> 16);
}
static __device__ __forceinline__ unsigned pack2bf(float a, float b) {
    return (unsigned)f2bf(a) | ((unsigned)f2bf(b) << 16);
}
template <int CTRL>
static __device__ __forceinline__ float max_ror(float v) {
    float r = __int_as_float(__builtin_amdgcn_update_dpp(
        __float_as_int(v), __float_as_int(v), CTRL, 0xf, 0xf, false));
    return fmaxf(v, r);
}
#define ROR8 0x128
#define ROR4 0x124
#define ROR2 0x122
#define ROR1 0x121

// feats LDS swizzle: row p (2048B rows), col = byte offset within row.
static __device__ __forceinline__ int fl(int p, int col) {
    return p * 2048 + (col ^ ((p & 7) << 4) ^ (((col >> 7) & 3) << 5));
}

// ---------------------------------------------------------------------------
// Kernel A1: transpose x [B][64][N] f32 -> xTB [B][N][64] bf16
// ---------------------------------------------------------------------------
__global__ __launch_bounds__(256) void transpose_x_kernel(
    const float* __restrict__ x, unsigned short* __restrict__ xTB)
{
    __shared__ float tile[64][65];
    const int b  = blockIdx.y;
    const int n0 = blockIdx.x * 64;
    const int tx = threadIdx.x & 63;
    const int ty = threadIdx.x >> 6;

    const float* xb = x + (size_t)b * CIN_ * N_;
    #pragma unroll
    for (int c = ty; c < 64; c += 4)
        tile[c][tx] = xb[(size_t)c * N_ + n0 + tx];
    __syncthreads();

    const int cp = threadIdx.x & 31;
    const int r0 = threadIdx.x >> 5;
    unsigned short* xTb = xTB + ((size_t)b * N_ + n0) * 64;
    #pragma unroll
    for (int nn = r0; nn < 64; nn += 8) {
        ushort2 v;
        v.x = f2bf(tile[2 * cp][nn]);
        v.y = f2bf(tile[2 * cp + 1][nn]);
        *(ushort2*)&xTb[(size_t)nn * 64 + 2 * cp] = v;
    }
}

// ---------------------------------------------------------------------------
// Kernel A2: pos [B][3][N] -> posT [B][N][4]
// ---------------------------------------------------------------------------
__global__ __launch_bounds__(256) void post_kernel(
    const float* __restrict__ pos, float* __restrict__ posT)
{
    const int b = blockIdx.y;
    const int n = blockIdx.x * 256 + threadIdx.x;
    const float* pb = pos + (size_t)b * 3 * N_;
    float4 v = make_float4(pb[n], pb[N_ + n], pb[2 * N_ + n], 0.0f);
    *(float4*)&posT[((size_t)b * N_ + n) * 4] = v;
}

// ---------------------------------------------------------------------------
// Kernel A3: wcv f32 [o][c][k] -> wcvB bf16 [o][k*64+c]  (k-major)
// ---------------------------------------------------------------------------
__global__ __launch_bounds__(256) void wcvb_kernel(
    const float* __restrict__ wcv, unsigned short* __restrict__ wcvB)
{
    const int i = blockIdx.x * 256 + threadIdx.x;   // over 64*1024
    const int o   = i >> 10;
    const int rem = i & 1023;
    const int k   = rem >> 6;
    const int c   = rem & 63;
    wcvB[i] = f2bf(wcv[(size_t)o * 1024 + c * 16 + k]);
}

// ---------------------------------------------------------------------------
// Fused kernel: 512 threads, 16 points.
//   w2/w3 m-part weights staged in LDS (uniform ds_read_b128 broadcast),
//   breaking the SMEM-reload + shared-lgkmcnt stall in the fc loops.
//   phase 1: fc pipeline (lane = neighbor); m3 frag -> aliased featsL head
//   phase 2: feats via MFMA -> swizzled featsL
//   phase 3: out[64 x 16] = wcvB . feats^T
// ---------------------------------------------------------------------------
__global__ __launch_bounds__(512) void fka_fused_kernel(
    const float* __restrict__ posT, const float* __restrict__ sup,
    const int*   __restrict__ nbr, const float* __restrict__ radius,
    const float* __restrict__ w1,  const float* __restrict__ w2,
    const float* __restrict__ w3,  const unsigned short* __restrict__ xTB,
    const unsigned short* __restrict__ wcvB,
    float* __restrict__ out)
{
    __shared__ unsigned short featsL[16 * 1024];  // 32KB; head of row p aliases m3 frag
    __shared__ int   idxs[16][32];
    __shared__ float t2s[16][16];
    __shared__ float pbuf[1024];                  // 4KB phase-3 partials
    __shared__ float w2m[256];                    // w2[k][0..15] row-major 16x16
    __shared__ float w3m[256];

    const int b  = blockIdx.y;
    const int t  = threadIdx.x;
    const int g  = t >> 5;             // point group 0..15
    const int n  = t & 31;
    const int s0 = blockIdx.x * 16;
    const int s  = s0 + g;

    // ---- stage fc m-part weights into LDS (one f32 per thread) ----
    if (t < 256) w2m[t] = w2[(t >> 4) * 32 + (t & 15)];
    else         w3m[t - 256] = w3[((t - 256) >> 4) * 32 + ((t - 256) & 15)];

    // ---- phase 1: fc pipeline (lane = neighbor), scalar f32 ----
    const int raw    = nbr[(((size_t)b * S_ + s) << 5) + n];
    const bool valid = raw > -1;
    const int id     = valid ? raw : 0;

    unsigned long long bal = __ballot(valid);
    unsigned bits = (unsigned)(bal >> (t & 32));
    const float nrm = sqrtf((float)__popc(bits));
    float dw = valid ? (1.0f / fmaxf(nrm, 1e-12f)) : 0.0f;

    const float4 pg = *(const float4*)&posT[((size_t)b * N_ + id) * 4];
    float px = pg.x - sup[(size_t)(b * 3 + 0) * S_ + s];
    float py = pg.y - sup[(size_t)(b * 3 + 1) * S_ + s];
    float pz = pg.z - sup[(size_t)(b * 3 + 2) * S_ + s];
    if (isinf(px)) dw = 0.0f;
    px = (isnan(px) || isinf(px)) ? 0.0f : px;
    py = (isnan(py) || isinf(py)) ? 0.0f : py;
    pz = (isnan(pz) || isinf(pz)) ? 0.0f : pz;
    const float inv_r = 1.0f / radius[0];
    px *= inv_r; py *= inv_r; pz *= inv_r;

    const int kk = n & 15;

    float m1[16], mp1[16], m2[16], mp2[16], m3[16];

    #pragma unroll
    for (int k = 0; k < 16; ++k) {
        float v = w1[k * 3 + 0] * px + w1[k * 3 + 1] * py + w1[k * 3 + 2] * pz;
        m1[k] = fmaxf(v, 0.0f) * dw;
    }
    #pragma unroll
    for (int k = 0; k < 16; ++k) {
        float v = m1[k];
        v = fmaxf(v, __shfl_xor(v, 16, 32));
        v = max_ror<ROR8>(v); v = max_ror<ROR4>(v);
        v = max_ror<ROR2>(v); v = max_ror<ROR1>(v);
        mp1[k] = v;
    }
    {
        const float* wb = &w2[kk * 32 + 16];
        float pa = 0.0f, pb = 0.0f;
        #pragma unroll
        for (int j = 0; j < 8; ++j) pa = fmaf(wb[j], mp1[j], pa);
        #pragma unroll
        for (int j = 0; j < 8; ++j) pb = fmaf(wb[8 + j], mp1[8 + j], pb);
        float tp = (n & 16) ? pb : pa;
        tp += __shfl_xor(tp, 16, 32);
        t2s[g][kk] = tp;
    }
    __syncthreads();   // w2m/w3m ready (also orders nothing else: t2s is wave-local)
    {
        float4 ta = *(const float4*)&t2s[g][0];
        float4 tb = *(const float4*)&t2s[g][4];
        float4 tc = *(const float4*)&t2s[g][8];
        float4 td = *(const float4*)&t2s[g][12];
        float t2v[16] = {ta.x, ta.y, ta.z, ta.w, tb.x, tb.y, tb.z, tb.w,
                         tc.x, tc.y, tc.z, tc.w, td.x, td.y, td.z, td.w};
        #pragma unroll
        for (int k = 0; k < 16; ++k) {
            const float* wr = &w2m[k * 16];
            float v = t2v[k];
            #pragma unroll
            for (int j4 = 0; j4 < 4; ++j4) {
                const float4 w4 = *(const float4*)&wr[j4 * 4];
                v = fmaf(w4.x, m1[j4 * 4 + 0], v);
                v = fmaf(w4.y, m1[j4 * 4 + 1], v);
                v = fmaf(w4.z, m1[j4 * 4 + 2], v);
                v = fmaf(w4.w, m1[j4 * 4 + 3], v);
            }
            m2[k] = fmaxf(v, 0.0f) * dw;
        }
    }
    #pragma unroll
    for (int k = 0; k < 16; ++k) {
        float v = m2[k];
        v = fmaxf(v, __shfl_xor(v, 16, 32));
        v = max_ror<ROR8>(v); v = max_ror<ROR4>(v);
        v = max_ror<ROR2>(v); v = max_ror<ROR1>(v);
        mp2[k] = v;
    }
    {
        const float* wb = &w3[kk * 32 + 16];
        float pa = 0.0f, pb = 0.0f;
        #pragma unroll
        for (int j = 0; j < 8; ++j) pa = fmaf(wb[j], mp2[j], pa);
        #pragma unroll
        for (int j = 0; j < 8; ++j) pb = fmaf(wb[8 + j], mp2[8 + j], pb);
        float tp = (n & 16) ? pb : pa;
        tp += __shfl_xor(tp, 16, 32);
        t2s[g][kk] = tp;
    }
    {
        float4 ta = *(const float4*)&t2s[g][0];
        float4 tb = *(const float4*)&t2s[g][4];
        float4 tc = *(const float4*)&t2s[g][8];
        float4 td = *(const float4*)&t2s[g][12];
        float t3v[16] = {ta.x, ta.y, ta.z, ta.w, tb.x, tb.y, tb.z, tb.w,
                         tc.x, tc.y, tc.z, tc.w, td.x, td.y, td.z, td.w};
        #pragma unroll
        for (int k = 0; k < 16; ++k) {
            const float* wr = &w3m[k * 16];
            float v = t3v[k];
            #pragma unroll
            for (int j4 = 0; j4 < 4; ++j4) {
                const float4 w4 = *(const float4*)&wr[j4 * 4];
                v = fmaf(w4.x, m2[j4 * 4 + 0], v);
                v = fmaf(w4.y, m2[j4 * 4 + 1], v);
                v = fmaf(w4.z, m2[j4 * 4 + 2], v);
                v = fmaf(w4.w, m2[j4 * 4 + 3], v);
            }
            m3[k] = fmaxf(v, 0.0f) * dw;
        }
    }

    idxs[g][n] = id;
    {
        // m3 B-frag aliased into head of featsL row g (offsets < 512 ushorts)
        const int hi = n >> 3, jj = n & 7;
        unsigned short* base = &featsL[g * 1024 + hi * 128 + jj];
        #pragma unroll
        for (int k = 0; k < 16; ++k) {
            const int row = (k + hi + g) & 15;
            base[row * 8] = f2bf(m3[k]);
        }
    }
    // wave-local production/consumption -> no barrier before phase 2

    // ---- phase 2: feats via MFMA (2 points per wave) -> swizzled LDS ----
    const int wv  = t >> 6;
    const int l   = t & 63;
    const int hi2 = l >> 4;
    const int k15 = l & 15;
    const unsigned short* xb = xTB + (size_t)b * N_ * 64;
    char* fLp = (char*)featsL;

    short8 bfrag[2];
    #pragma unroll
    for (int pp = 0; pp < 2; ++pp) {
        const int p = wv * 2 + pp;
        const int brow = (k15 + hi2 + p) & 15;
        bfrag[pp] = *(const short8*)&featsL[p * 1024 + hi2 * 128 + brow * 8];
    }

    #pragma unroll
    for (int pp = 0; pp < 2; ++pp) {
        const int p = wv * 2 + pp;

        int ids8[8];
        #pragma unroll
        for (int j = 0; j < 8; ++j) ids8[j] = idxs[p][hi2 * 8 + j];

        f32x4a acc[4];
        #pragma unroll
        for (int ct = 0; ct < 4; ++ct) acc[ct] = (f32x4a){0.f, 0.f, 0.f, 0.f};

        #pragma unroll
        for (int ct = 0; ct < 4; ++ct) {
            union { unsigned short u[8]; short8 v; } A;
            #pragma unroll
            for (int j = 0; j < 8; ++j)
                A.u[j] = xb[((size_t)ids8[j] << 6) + ct * 16 + k15];
            acc[ct] = __builtin_amdgcn_mfma_f32_16x16x32_bf16(A.v, bfrag[pp], acc[ct], 0, 0, 0);
        }

        #pragma unroll
        for (int ct = 0; ct < 4; ++ct) {
            uint2 val;
            val.x = pack2bf(acc[ct][0], acc[ct][1]);
            val.y = pack2bf(acc[ct][2], acc[ct][3]);
            const int col = k15 * 128 + ct * 32 + hi2 * 8;
            *(uint2*)(fLp + fl(p, col)) = val;   // own row only
        }
    }
    __syncthreads();

    // ---- phase 3: out tile 64 x 16. wave = (o-tile 0..3, k-half 0..1) ----
    const int ot  = wv & 3;
    const int kh  = wv >> 2;
    const int lq  = hi2;
    const int l15 = k15;

    const unsigned short* apod =
        wcvB + (size_t)(ot * 16 + l15) * 1024 + kh * 512 + lq * 8;

    f32x4a oacc = (f32x4a){0.f, 0.f, 0.f, 0.f};
    #pragma unroll 4
    for (int ks = 0; ks < 16; ++ks) {
        const int col = kh * 1024 + ks * 64 + lq * 16;
        short8 bfv = *(const short8*)(fLp + fl(l15, col));
        short8 afv = *(const short8*)(apod + ks * 32);
        oacc = __builtin_amdgcn_mfma_f32_16x16x32_bf16(afv, bfv, oacc, 0, 0, 0);
    }

    if (kh == 1) {
        #pragma unroll
        for (int r = 0; r < 4; ++r)
            pbuf[ot * 256 + (lq * 4 + r) * 16 + l15] = oacc[r];
    }
    __syncthreads();
    if (kh == 0) {
        const int sidx = s0 + l15;
        const bool infs = isinf(sup[(size_t)b * 3 * S_ + sidx]);
        #pragma unroll
        for (int r = 0; r < 4; ++r) {
            const float v = oacc[r] + pbuf[ot * 256 + (lq * 4 + r) * 16 + l15];
            const int o = ot * 16 + lq * 4 + r;
            out[((size_t)b * COUT_ + o) * S_ + sidx] = infs ? INFINITY : v;
        }
    }
}

// ---------------------------------------------------------------------------
extern "C" void kernel_launch(void* const* d_in, const int* in_sizes, int n_in,
                              void* d_out, int out_size, void* d_ws, size_t ws_size,
                              hipStream_t stream)
{
    const float* x   = (const float*)d_in[0];
    const float* pos = (const float*)d_in[1];
    const float* sup = (const float*)d_in[2];
    const int*   nbr = (const int*)d_in[3];
    const float* rad = (const float*)d_in[4];
    const float* w1  = (const float*)d_in[5];
    const float* w2  = (const float*)d_in[6];
    const float* w3  = (const float*)d_in[7];
    const float* wcv = (const float*)d_in[8];
    float* out = (float*)d_out;

    char* p = (char*)d_ws;
    unsigned short* xTB = (unsigned short*)p;  p += (size_t)B_ * N_ * 64 * sizeof(unsigned short);
    float* posT = (float*)p;                   p += (size_t)B_ * N_ * 4 * sizeof(float);
    unsigned short* wcvB = (unsigned short*)p; p += (size_t)COUT_ * 1024 * sizeof(unsigned short);

    transpose_x_kernel<<<dim3(N_ / 64, B_), 256, 0, stream>>>(x, xTB);
    post_kernel<<<dim3(N_ / 256, B_), 256, 0, stream>>>(pos, posT);
    wcvb_kernel<<<dim3(256), 256, 0, stream>>>(wcv, wcvB);

    fka_fused_kernel<<<dim3(S_ / 16, B_), 512, 0, stream>>>(
        posT, sup, nbr, rad, w1, w2, w3, xTB, wcvB, out);
}

// Round 13
// 82.736 us; speedup vs baseline: 1.1134x; 1.1134x over previous
//
#include <hip/hip_runtime.h>
#include <math.h>

#define B_    4
#define CIN_  64
#define COUT_ 64
#define N_    32768
#define S_    8192

typedef __attribute__((ext_vector_type(8))) short short8;
typedef __attribute__((ext_vector_type(4))) float f32x4a;

static __device__ __forceinline__ unsigned short f2bf(float x) {
    unsigned u = __float_as_uint(x);
    u += 0x7fffu + ((u >> 16) & 1u);
    return (unsigned short)(u >> 16);
}
static __device__ __forceinline__ unsigned pack2bf(float a, float b) {
    return (unsigned)f2bf(a) | ((unsigned)f2bf(b) << 16);
}
template <int CTRL>
static __device__ __forceinline__ float max_ror(float v) {
    float r = __int_as_float(__builtin_amdgcn_update_dpp(
        __float_as_int(v), __float_as_int(v), CTRL, 0xf, 0xf, false));
    return fmaxf(v, r);
}
#define ROR8 0x128
#define ROR4 0x124
#define ROR2 0x122
#define ROR1 0x121

// feats LDS swizzle: row p (2048B rows), col = byte offset within row.
static __device__ __forceinline__ int fl(int p, int col) {
    return p * 2048 + (col ^ ((p & 7) << 4) ^ (((col >> 7) & 3) << 5));
}

// ---------------------------------------------------------------------------
// Kernel A1: transpose x [B][64][N] f32 -> xTB [B][N][64] bf16
// ---------------------------------------------------------------------------
__global__ __launch_bounds__(256) void transpose_x_kernel(
    const float* __restrict__ x, unsigned short* __restrict__ xTB)
{
    __shared__ float tile[64][65];
    const int b  = blockIdx.y;
    const int n0 = blockIdx.x * 64;
    const int tx = threadIdx.x & 63;
    const int ty = threadIdx.x >> 6;

    const float* xb = x + (size_t)b * CIN_ * N_;
    #pragma unroll
    for (int c = ty; c < 64; c += 4)
        tile[c][tx] = xb[(size_t)c * N_ + n0 + tx];
    __syncthreads();

    const int cp = threadIdx.x & 31;
    const int r0 = threadIdx.x >> 5;
    unsigned short* xTb = xTB + ((size_t)b * N_ + n0) * 64;
    #pragma unroll
    for (int nn = r0; nn < 64; nn += 8) {
        ushort2 v;
        v.x = f2bf(tile[2 * cp][nn]);
        v.y = f2bf(tile[2 * cp + 1][nn]);
        *(ushort2*)&xTb[(size_t)nn * 64 + 2 * cp] = v;
    }
}

// ---------------------------------------------------------------------------
// Kernel A2: pos [B][3][N] -> posT [B][N][4]
// ---------------------------------------------------------------------------
__global__ __launch_bounds__(256) void post_kernel(
    const float* __restrict__ pos, float* __restrict__ posT)
{
    const int b = blockIdx.y;
    const int n = blockIdx.x * 256 + threadIdx.x;
    const float* pb = pos + (size_t)b * 3 * N_;
    float4 v = make_float4(pb[n], pb[N_ + n], pb[2 * N_ + n], 0.0f);
    *(float4*)&posT[((size_t)b * N_ + n) * 4] = v;
}

// ---------------------------------------------------------------------------
// Kernel A3: wcv f32 [o][c][k] -> wcvB bf16 [o][k*64+c]  (k-major)
// ---------------------------------------------------------------------------
__global__ __launch_bounds__(256) void wcvb_kernel(
    const float* __restrict__ wcv, unsigned short* __restrict__ wcvB)
{
    const int i = blockIdx.x * 256 + threadIdx.x;   // over 64*1024
    const int o   = i >> 10;
    const int rem = i & 1023;
    const int k   = rem >> 6;
    const int c   = rem & 63;
    wcvB[i] = f2bf(wcv[(size_t)o * 1024 + c * 16 + k]);
}

// ---------------------------------------------------------------------------
// Fused kernel: 512 threads, 16 points (2 per wave; all fc exchange wave-local)
//   T14 async-split: x-gathers for point 0 issued mid-phase-1 (hidden under
//   fc2/mp2/t3/fc3); point-1 gathers issued at top of phase 2 (hidden under
//   point-0 MFMA+pack). wb2/wb3 weight loads hoisted before t2. ids via shfl
//   (no idxs LDS).
// ---------------------------------------------------------------------------
__global__ __launch_bounds__(512) void fka_fused_kernel(
    const float* __restrict__ posT, const float* __restrict__ sup,
    const int*   __restrict__ nbr, const float* __restrict__ radius,
    const float* __restrict__ w1,  const float* __restrict__ w2,
    const float* __restrict__ w3,  const unsigned short* __restrict__ xTB,
    const unsigned short* __restrict__ wcvB,
    float* __restrict__ out)
{
    __shared__ unsigned short featsL[16 * 1024];  // 32KB; head of row p aliases m3 frag
    __shared__ float t2s[16][16];
    __shared__ float pbuf[1024];                  // 4KB phase-3 partials

    const int b  = blockIdx.y;
    const int t  = threadIdx.x;
    const int g  = t >> 5;             // point group 0..15
    const int n  = t & 31;
    const int s0 = blockIdx.x * 16;
    const int s  = s0 + g;
    const int wv = t >> 6;
    const int l  = t & 63;
    const int hi2 = l >> 4;            // 0..3
    const int k15 = l & 15;

    // ---- top: neighbor ids + dw ----
    const int raw    = nbr[(((size_t)b * S_ + s) << 5) + n];
    const bool valid = raw > -1;
    const int id     = valid ? raw : 0;

    unsigned long long bal = __ballot(valid);
    unsigned bits = (unsigned)(bal >> (t & 32));
    const float nrm = sqrtf((float)__popc(bits));
    float dw = valid ? (1.0f / fmaxf(nrm, 1e-12f)) : 0.0f;

    // gather ids for this wave's two points (wave-local shfl; no LDS)
    int ids0[8], ids1[8];
    #pragma unroll
    for (int j = 0; j < 8; ++j) {
        ids0[j] = __shfl(id, hi2 * 8 + j, 64);
        ids1[j] = __shfl(id, 32 + hi2 * 8 + j, 64);
    }

    const float4 pg = *(const float4*)&posT[((size_t)b * N_ + id) * 4];
    float px = pg.x - sup[(size_t)(b * 3 + 0) * S_ + s];
    float py = pg.y - sup[(size_t)(b * 3 + 1) * S_ + s];
    float pz = pg.z - sup[(size_t)(b * 3 + 2) * S_ + s];
    if (isinf(px)) dw = 0.0f;
    px = (isnan(px) || isinf(px)) ? 0.0f : px;
    py = (isnan(py) || isinf(py)) ? 0.0f : py;
    pz = (isnan(pz) || isinf(pz)) ? 0.0f : pz;
    const float inv_r = 1.0f / radius[0];
    px *= inv_r; py *= inv_r; pz *= inv_r;

    const int kk = n & 15;
    const unsigned short* xb = xTB + (size_t)b * N_ * 64;

    float m1[16], mp1[16], m2[16], mp2[16], m3[16];

    // ---- fc1 (scalar f32, exact) ----
    #pragma unroll
    for (int k = 0; k < 16; ++k) {
        float v = w1[k * 3 + 0] * px + w1[k * 3 + 1] * py + w1[k * 3 + 2] * pz;
        m1[k] = fmaxf(v, 0.0f) * dw;
    }
    // ---- mp1: shfl xor16 + DPP ror (exact) ----
    #pragma unroll
    for (int k = 0; k < 16; ++k) {
        float v = m1[k];
        v = fmaxf(v, __shfl_xor(v, 16, 32));
        v = max_ror<ROR8>(v); v = max_ror<ROR4>(v);
        v = max_ror<ROR2>(v); v = max_ror<ROR1>(v);
        mp1[k] = v;
    }

    // ---- hoist per-lane mp-weight rows (w2, w3) as float4 loads ----
    float wb2r[16], wb3r[16];
    {
        const float* wp2 = &w2[kk * 32 + 16];
        const float* wp3 = &w3[kk * 32 + 16];
        #pragma unroll
        for (int q = 0; q < 4; ++q) {
            *(float4*)&wb2r[q * 4] = *(const float4*)&wp2[q * 4];
            *(float4*)&wb3r[q * 4] = *(const float4*)&wp3[q * 4];
        }
    }

    // ---- t2 cooperative bias ----
    {
        float pa = 0.0f, pb = 0.0f;
        #pragma unroll
        for (int j = 0; j < 8; ++j) pa = fmaf(wb2r[j], mp1[j], pa);
        #pragma unroll
        for (int j = 0; j < 8; ++j) pb = fmaf(wb2r[8 + j], mp1[8 + j], pb);
        float tp = (n & 16) ? pb : pa;
        tp += __shfl_xor(tp, 16, 32);
        t2s[g][kk] = tp;
    }

    // ---- EARLY PREFETCH: point-0 gathers (hidden under fc2/mp2/t3/fc3) ----
    unsigned short xp0[4][8];
    #pragma unroll
    for (int ct = 0; ct < 4; ++ct)
        #pragma unroll
        for (int j = 0; j < 8; ++j)
            xp0[ct][j] = xb[((size_t)ids0[j] << 6) + ct * 16 + k15];

    // ---- fc2 m-part (uniform w2 rows -> scalar loads) ----
    {
        float4 ta = *(const float4*)&t2s[g][0];
        float4 tb = *(const float4*)&t2s[g][4];
        float4 tc = *(const float4*)&t2s[g][8];
        float4 td = *(const float4*)&t2s[g][12];
        float t2v[16] = {ta.x, ta.y, ta.z, ta.w, tb.x, tb.y, tb.z, tb.w,
                         tc.x, tc.y, tc.z, tc.w, td.x, td.y, td.z, td.w};
        #pragma unroll
        for (int k = 0; k < 16; ++k) {
            const float* wr = &w2[k * 32];
            float v = t2v[k];
            #pragma unroll
            for (int j = 0; j < 16; ++j) v = fmaf(wr[j], m1[j], v);
            m2[k] = fmaxf(v, 0.0f) * dw;
        }
    }
    // ---- mp2 ----
    #pragma unroll
    for (int k = 0; k < 16; ++k) {
        float v = m2[k];
        v = fmaxf(v, __shfl_xor(v, 16, 32));
        v = max_ror<ROR8>(v); v = max_ror<ROR4>(v);
        v = max_ror<ROR2>(v); v = max_ror<ROR1>(v);
        mp2[k] = v;
    }
    // ---- t3 cooperative bias (weights already in regs) ----
    {
        float pa = 0.0f, pb = 0.0f;
        #pragma unroll
        for (int j = 0; j < 8; ++j) pa = fmaf(wb3r[j], mp2[j], pa);
        #pragma unroll
        for (int j = 0; j < 8; ++j) pb = fmaf(wb3r[8 + j], mp2[8 + j], pb);
        float tp = (n & 16) ? pb : pa;
        tp += __shfl_xor(tp, 16, 32);
        t2s[g][kk] = tp;
    }
    // ---- fc3 m-part ----
    {
        float4 ta = *(const float4*)&t2s[g][0];
        float4 tb = *(const float4*)&t2s[g][4];
        float4 tc = *(const float4*)&t2s[g][8];
        float4 td = *(const float4*)&t2s[g][12];
        float t3v[16] = {ta.x, ta.y, ta.z, ta.w, tb.x, tb.y, tb.z, tb.w,
                         tc.x, tc.y, tc.z, tc.w, td.x, td.y, td.z, td.w};
        #pragma unroll
        for (int k = 0; k < 16; ++k) {
            const float* wr = &w3[k * 32];
            float v = t3v[k];
            #pragma unroll
            for (int j = 0; j < 16; ++j) v = fmaf(wr[j], m2[j], v);
            m3[k] = fmaxf(v, 0.0f) * dw;
        }
    }

    // ---- m3 B-frag -> aliased head of featsL row g (wave-local) ----
    {
        const int hi = n >> 3, jj = n & 7;
        unsigned short* base = &featsL[g * 1024 + hi * 128 + jj];
        #pragma unroll
        for (int k = 0; k < 16; ++k) {
            const int row = (k + hi + g) & 15;
            base[row * 8] = f2bf(m3[k]);
        }
    }
    // wave-local production/consumption -> no barrier before phase 2

    // ---- phase 2 ----
    char* fLp = (char*)featsL;

    // B-frags from aliased heads (before any featsL overwrite)
    short8 bfrag[2];
    #pragma unroll
    for (int pp = 0; pp < 2; ++pp) {
        const int p = wv * 2 + pp;
        const int brow = (k15 + hi2 + p) & 15;
        bfrag[pp] = *(const short8*)&featsL[p * 1024 + hi2 * 128 + brow * 8];
    }

    // issue point-1 gathers now (consumed after point-0 MFMAs)
    unsigned short xp1[4][8];
    #pragma unroll
    for (int ct = 0; ct < 4; ++ct)
        #pragma unroll
        for (int j = 0; j < 8; ++j)
            xp1[ct][j] = xb[((size_t)ids1[j] << 6) + ct * 16 + k15];

    // point 0: MFMA + pack + store
    {
        const int p = wv * 2;
        #pragma unroll
        for (int ct = 0; ct < 4; ++ct) {
            union { unsigned short u[8]; short8 v; } A;
            #pragma unroll
            for (int j = 0; j < 8; ++j) A.u[j] = xp0[ct][j];
            f32x4a acc = (f32x4a){0.f, 0.f, 0.f, 0.f};
            acc = __builtin_amdgcn_mfma_f32_16x16x32_bf16(A.v, bfrag[0], acc, 0, 0, 0);
            uint2 val;
            val.x = pack2bf(acc[0], acc[1]);
            val.y = pack2bf(acc[2], acc[3]);
            const int col = k15 * 128 + ct * 32 + hi2 * 8;
            *(uint2*)(fLp + fl(p, col)) = val;
        }
    }
    // point 1: MFMA + pack + store
    {
        const int p = wv * 2 + 1;
        #pragma unroll
        for (int ct = 0; ct < 4; ++ct) {
            union { unsigned short u[8]; short8 v; } A;
            #pragma unroll
            for (int j = 0; j < 8; ++j) A.u[j] = xp1[ct][j];
            f32x4a acc = (f32x4a){0.f, 0.f, 0.f, 0.f};
            acc = __builtin_amdgcn_mfma_f32_16x16x32_bf16(A.v, bfrag[1], acc, 0, 0, 0);
            uint2 val;
            val.x = pack2bf(acc[0], acc[1]);
            val.y = pack2bf(acc[2], acc[3]);
            const int col = k15 * 128 + ct * 32 + hi2 * 8;
            *(uint2*)(fLp + fl(p, col)) = val;
        }
    }
    __syncthreads();

    // ---- phase 3: out tile 64 x 16. wave = (o-tile 0..3, k-half 0..1) ----
    const int ot  = wv & 3;
    const int kh  = wv >> 2;
    const int lq  = hi2;
    const int l15 = k15;

    const unsigned short* apod =
        wcvB + (size_t)(ot * 16 + l15) * 1024 + kh * 512 + lq * 8;

    f32x4a oacc = (f32x4a){0.f, 0.f, 0.f, 0.f};
    #pragma unroll 4
    for (int ks = 0; ks < 16; ++ks) {
        const int col = kh * 1024 + ks * 64 + lq * 16;
        short8 bfv = *(const short8*)(fLp + fl(l15, col));
        short8 afv = *(const short8*)(apod + ks * 32);
        oacc = __builtin_amdgcn_mfma_f32_16x16x32_bf16(afv, bfv, oacc, 0, 0, 0);
    }

    if (kh == 1) {
        #pragma unroll
        for (int r = 0; r < 4; ++r)
            pbuf[ot * 256 + (lq * 4 + r) * 16 + l15] = oacc[r];
    }
    __syncthreads();
    if (kh == 0) {
        const int sidx = s0 + l15;
        const bool infs = isinf(sup[(size_t)b * 3 * S_ + sidx]);
        #pragma unroll
        for (int r = 0; r < 4; ++r) {
            const float v = oacc[r] + pbuf[ot * 256 + (lq * 4 + r) * 16 + l15];
            const int o = ot * 16 + lq * 4 + r;
            out[((size_t)b * COUT_ + o) * S_ + sidx] = infs ? INFINITY : v;
        }
    }
}

// ---------------------------------------------------------------------------
extern "C" void kernel_launch(void* const* d_in, const int* in_sizes, int n_in,
                              void* d_out, int out_size, void* d_ws, size_t ws_size,
                              hipStream_t stream)
{
    const float* x   = (const float*)d_in[0];
    const float* pos = (const float*)d_in[1];
    const float* sup = (const float*)d_in[2];
    const int*   nbr = (const int*)d_in[3];
    const float* rad = (const float*)d_in[4];
    const float* w1  = (const float*)d_in[5];
    const float* w2  = (const float*)d_in[6];
    const float* w3  = (const float*)d_in[7];
    const float* wcv = (const float*)d_in[8];
    float* out = (float*)d_out;

    char* p = (char*)d_ws;
    unsigned short* xTB = (unsigned short*)p;  p += (size_t)B_ * N_ * 64 * sizeof(unsigned short);
    float* posT = (float*)p;                   p += (size_t)B_ * N_ * 4 * sizeof(float);
    unsigned short* wcvB = (unsigned short*)p; p += (size_t)COUT_ * 1024 * sizeof(unsigned short);

    transpose_x_kernel<<<dim3(N_ / 64, B_), 256, 0, stream>>>(x, xTB);
    post_kernel<<<dim3(N_ / 256, B_), 256, 0, stream>>>(pos, posT);
    wcvb_kernel<<<dim3(256), 256, 0, stream>>>(wcv, wcvB);

    fka_fused_kernel<<<dim3(S_ / 16, B_), 512, 0, stream>>>(
        posT, sup, nbr, rad, w1, w2, w3, xTB, wcvB, out);
}

// Round 14
// 76.621 us; speedup vs baseline: 1.2022x; 1.0798x over previous
//
#include <hip/hip_runtime.h>
#include <math.h>

#define B_    4
#define CIN_  64
#define COUT_ 64
#define N_    32768
#define S_    8192

typedef __attribute__((ext_vector_type(8))) short short8;
typedef __attribute__((ext_vector_type(4))) float f32x4a;

static __device__ __forceinline__ unsigned short f2bf(float x) {
    unsigned u = __float_as_uint(x);
    u += 0x7fffu + ((u >> 16) & 1u);
    return (unsigned short)(u >> 16);
}
static __device__ __forceinline__ unsigned pack2bf(float a, float b) {
    return (unsigned)f2bf(a) | ((unsigned)f2bf(b) << 16);
}
template <int CTRL>
static __device__ __forceinline__ float max_ror(float v) {
    float r = __int_as_float(__builtin_amdgcn_update_dpp(
        __float_as_int(v), __float_as_int(v), CTRL, 0xf, 0xf, false));
    return fmaxf(v, r);
}
#define ROR8 0x128
#define ROR4 0x124
#define ROR2 0x122
#define ROR1 0x121

// feats LDS swizzle: row p (2048B rows), col = byte offset within row.
// Second XOR now spreads k (col bits 7-9) over bank bits 4-6: write
// conflicts drop 4-way -> 2-way; reads stay at BW floor. Bits >=4 only,
// so 8B writes / 16B reads keep alignment; bijective per (p, col>>7).
static __device__ __forceinline__ int fl(int p, int col) {
    return p * 2048 + (col ^ ((p & 7) << 4) ^ (((col >> 7) & 7) << 4));
}

// ---------------------------------------------------------------------------
// Merged prep kernel (one launch instead of three):
//   blocks [0, 2048)        : transpose x [B][64][N] f32 -> xTB [B][N][64] bf16
//   blocks [2048, 2560)     : pos [B][3][N] -> posT [B][N][4]
//   blocks [2560, 2816)     : wcv f32 [o][c][k] -> wcvB bf16 [o][k*64+c]
// ---------------------------------------------------------------------------
__global__ __launch_bounds__(256) void prep_kernel(
    const float* __restrict__ x,   unsigned short* __restrict__ xTB,
    const float* __restrict__ pos, float* __restrict__ posT,
    const float* __restrict__ wcv, unsigned short* __restrict__ wcvB)
{
    const int bid = blockIdx.x;

    if (bid < 2048) {
        // ---- transpose x ----
        __shared__ float tile[64][65];
        const int b  = bid >> 9;            // /512
        const int n0 = (bid & 511) * 64;
        const int tx = threadIdx.x & 63;
        const int ty = threadIdx.x >> 6;

        const float* xb = x + (size_t)b * CIN_ * N_;
        #pragma unroll
        for (int c = ty; c < 64; c += 4)
            tile[c][tx] = xb[(size_t)c * N_ + n0 + tx];
        __syncthreads();

        const int cp = threadIdx.x & 31;
        const int r0 = threadIdx.x >> 5;
        unsigned short* xTb = xTB + ((size_t)b * N_ + n0) * 64;
        #pragma unroll
        for (int nn = r0; nn < 64; nn += 8) {
            ushort2 v;
            v.x = f2bf(tile[2 * cp][nn]);
            v.y = f2bf(tile[2 * cp + 1][nn]);
            *(ushort2*)&xTb[(size_t)nn * 64 + 2 * cp] = v;
        }
    } else if (bid < 2560) {
        // ---- posT ----
        const int r = bid - 2048;
        const int b = r >> 7;               // /128
        const int n = (r & 127) * 256 + threadIdx.x;
        const float* pb = pos + (size_t)b * 3 * N_;
        float4 v = make_float4(pb[n], pb[N_ + n], pb[2 * N_ + n], 0.0f);
        *(float4*)&posT[((size_t)b * N_ + n) * 4] = v;
    } else {
        // ---- wcvB ----
        const int i = (bid - 2560) * 256 + threadIdx.x;   // over 64*1024
        const int o   = i >> 10;
        const int rem = i & 1023;
        const int k   = rem >> 6;
        const int c   = rem & 63;
        wcvB[i] = f2bf(wcv[(size_t)o * 1024 + c * 16 + k]);
    }
}

// ---------------------------------------------------------------------------
// Fused kernel: 512 threads, 16 points (r11 structure).
//   phase 1: fc pipeline (lane = neighbor); m3 frag -> aliased featsL head
//   phase 2: read own B-frags to regs first, gather + MFMA -> swizzled featsL
//   phase 3: out[64 x 16] = wcvB . feats^T
// LDS = 32K featsL + 2K idxs + 1K t2s + 4K pbuf = 39K.
// ---------------------------------------------------------------------------
__global__ __launch_bounds__(512) void fka_fused_kernel(
    const float* __restrict__ posT, const float* __restrict__ sup,
    const int*   __restrict__ nbr, const float* __restrict__ radius,
    const float* __restrict__ w1,  const float* __restrict__ w2,
    const float* __restrict__ w3,  const unsigned short* __restrict__ xTB,
    const unsigned short* __restrict__ wcvB,
    float* __restrict__ out)
{
    __shared__ unsigned short featsL[16 * 1024];  // 32KB; head of row p aliases m3 frag
    __shared__ int   idxs[16][32];
    __shared__ float t2s[16][16];
    __shared__ float pbuf[1024];                  // 4KB phase-3 partials

    const int b  = blockIdx.y;
    const int t  = threadIdx.x;
    const int g  = t >> 5;             // point group 0..15
    const int n  = t & 31;
    const int s0 = blockIdx.x * 16;
    const int s  = s0 + g;

    // ---- phase 1: fc pipeline (lane = neighbor), scalar f32 ----
    const int raw    = nbr[(((size_t)b * S_ + s) << 5) + n];
    const bool valid = raw > -1;
    const int id     = valid ? raw : 0;

    unsigned long long bal = __ballot(valid);
    unsigned bits = (unsigned)(bal >> (t & 32));
    const float nrm = sqrtf((float)__popc(bits));
    float dw = valid ? (1.0f / fmaxf(nrm, 1e-12f)) : 0.0f;

    const float4 pg = *(const float4*)&posT[((size_t)b * N_ + id) * 4];
    float px = pg.x - sup[(size_t)(b * 3 + 0) * S_ + s];
    float py = pg.y - sup[(size_t)(b * 3 + 1) * S_ + s];
    float pz = pg.z - sup[(size_t)(b * 3 + 2) * S_ + s];
    if (isinf(px)) dw = 0.0f;
    px = (isnan(px) || isinf(px)) ? 0.0f : px;
    py = (isnan(py) || isinf(py)) ? 0.0f : py;
    pz = (isnan(pz) || isinf(pz)) ? 0.0f : pz;
    const float inv_r = 1.0f / radius[0];
    px *= inv_r; py *= inv_r; pz *= inv_r;

    const int kk = n & 15;

    float m1[16], mp1[16], m2[16], mp2[16], m3[16];

    #pragma unroll
    for (int k = 0; k < 16; ++k) {
        float v = w1[k * 3 + 0] * px + w1[k * 3 + 1] * py + w1[k * 3 + 2] * pz;
        m1[k] = fmaxf(v, 0.0f) * dw;
    }
    #pragma unroll
    for (int k = 0; k < 16; ++k) {
        float v = m1[k];
        v = fmaxf(v, __shfl_xor(v, 16, 32));
        v = max_ror<ROR8>(v); v = max_ror<ROR4>(v);
        v = max_ror<ROR2>(v); v = max_ror<ROR1>(v);
        mp1[k] = v;
    }
    {
        const float* wb = &w2[kk * 32 + 16];
        float pa = 0.0f, pb = 0.0f;
        #pragma unroll
        for (int j = 0; j < 8; ++j) pa = fmaf(wb[j], mp1[j], pa);
        #pragma unroll
        for (int j = 0; j < 8; ++j) pb = fmaf(wb[8 + j], mp1[8 + j], pb);
        float tp = (n & 16) ? pb : pa;
        tp += __shfl_xor(tp, 16, 32);
        t2s[g][kk] = tp;
    }
    {
        float4 ta = *(const float4*)&t2s[g][0];
        float4 tb = *(const float4*)&t2s[g][4];
        float4 tc = *(const float4*)&t2s[g][8];
        float4 td = *(const float4*)&t2s[g][12];
        float t2v[16] = {ta.x, ta.y, ta.z, ta.w, tb.x, tb.y, tb.z, tb.w,
                         tc.x, tc.y, tc.z, tc.w, td.x, td.y, td.z, td.w};
        #pragma unroll
        for (int k = 0; k < 16; ++k) {
            const float* wr = &w2[k * 32];
            float v = t2v[k];
            #pragma unroll
            for (int j = 0; j < 16; ++j) v = fmaf(wr[j], m1[j], v);
            m2[k] = fmaxf(v, 0.0f) * dw;
        }
    }
    #pragma unroll
    for (int k = 0; k < 16; ++k) {
        float v = m2[k];
        v = fmaxf(v, __shfl_xor(v, 16, 32));
        v = max_ror<ROR8>(v); v = max_ror<ROR4>(v);
        v = max_ror<ROR2>(v); v = max_ror<ROR1>(v);
        mp2[k] = v;
    }
    {
        const float* wb = &w3[kk * 32 + 16];
        float pa = 0.0f, pb = 0.0f;
        #pragma unroll
        for (int j = 0; j < 8; ++j) pa = fmaf(wb[j], mp2[j], pa);
        #pragma unroll
        for (int j = 0; j < 8; ++j) pb = fmaf(wb[8 + j], mp2[8 + j], pb);
        float tp = (n & 16) ? pb : pa;
        tp += __shfl_xor(tp, 16, 32);
        t2s[g][kk] = tp;
    }
    {
        float4 ta = *(const float4*)&t2s[g][0];
        float4 tb = *(const float4*)&t2s[g][4];
        float4 tc = *(const float4*)&t2s[g][8];
        float4 td = *(const float4*)&t2s[g][12];
        float t3v[16] = {ta.x, ta.y, ta.z, ta.w, tb.x, tb.y, tb.z, tb.w,
                         tc.x, tc.y, tc.z, tc.w, td.x, td.y, td.z, td.w};
        #pragma unroll
        for (int k = 0; k < 16; ++k) {
            const float* wr = &w3[k * 32];
            float v = t3v[k];
            #pragma unroll
            for (int j = 0; j < 16; ++j) v = fmaf(wr[j], m2[j], v);
            m3[k] = fmaxf(v, 0.0f) * dw;
        }
    }

    idxs[g][n] = id;
    {
        // m3 B-frag aliased into head of featsL row g (offsets < 512 ushorts)
        const int hi = n >> 3, jj = n & 7;
        unsigned short* base = &featsL[g * 1024 + hi * 128 + jj];
        #pragma unroll
        for (int k = 0; k < 16; ++k) {
            const int row = (k + hi + g) & 15;
            base[row * 8] = f2bf(m3[k]);
        }
    }
    // all of the above is wave-local (p = 2wv, 2wv+1) -> NO barrier here

    // ---- phase 2: feats via MFMA (2 points per wave) -> swizzled LDS ----
    const int wv  = t >> 6;
    const int l   = t & 63;
    const int hi2 = l >> 4;
    const int k15 = l & 15;
    const unsigned short* xb = xTB + (size_t)b * N_ * 64;
    char* fLp = (char*)featsL;

    // read BOTH B-frags from the aliased region before any featsL write
    short8 bfrag[2];
    #pragma unroll
    for (int pp = 0; pp < 2; ++pp) {
        const int p = wv * 2 + pp;
        const int brow = (k15 + hi2 + p) & 15;
        bfrag[pp] = *(const short8*)&featsL[p * 1024 + hi2 * 128 + brow * 8];
    }

    #pragma unroll
    for (int pp = 0; pp < 2; ++pp) {
        const int p = wv * 2 + pp;

        int ids8[8];
        #pragma unroll
        for (int j = 0; j < 8; ++j) ids8[j] = idxs[p][hi2 * 8 + j];

        f32x4a acc[4];
        #pragma unroll
        for (int ct = 0; ct < 4; ++ct) acc[ct] = (f32x4a){0.f, 0.f, 0.f, 0.f};

        #pragma unroll
        for (int ct = 0; ct < 4; ++ct) {
            union { unsigned short u[8]; short8 v; } A;
            #pragma unroll
            for (int j = 0; j < 8; ++j)
                A.u[j] = xb[((size_t)ids8[j] << 6) + ct * 16 + k15];
            acc[ct] = __builtin_amdgcn_mfma_f32_16x16x32_bf16(A.v, bfrag[pp], acc[ct], 0, 0, 0);
        }

        // acc[ct][r] = feats[c = ct*16 + hi2*4 + r][k = k15]; k-major idx = k*64+c
        #pragma unroll
        for (int ct = 0; ct < 4; ++ct) {
            uint2 val;
            val.x = pack2bf(acc[ct][0], acc[ct][1]);
            val.y = pack2bf(acc[ct][2], acc[ct][3]);
            const int col = k15 * 128 + ct * 32 + hi2 * 8;
            *(uint2*)(fLp + fl(p, col)) = val;   // own row only (p = 2wv+pp)
        }
    }
    __syncthreads();

    // ---- phase 3: out tile 64 x 16. wave = (o-tile 0..3, k-half 0..1) ----
    const int ot  = wv & 3;
    const int kh  = wv >> 2;
    const int lq  = hi2;
    const int l15 = k15;

    const unsigned short* apod =
        wcvB + (size_t)(ot * 16 + l15) * 1024 + kh * 512 + lq * 8;

    f32x4a oacc = (f32x4a){0.f, 0.f, 0.f, 0.f};
    #pragma unroll 4
    for (int ks = 0; ks < 16; ++ks) {
        const int col = kh * 1024 + ks * 64 + lq * 16;
        short8 bfv = *(const short8*)(fLp + fl(l15, col));
        short8 afv = *(const short8*)(apod + ks * 32);
        oacc = __builtin_amdgcn_mfma_f32_16x16x32_bf16(afv, bfv, oacc, 0, 0, 0);
    }

    if (kh == 1) {
        #pragma unroll
        for (int r = 0; r < 4; ++r)
            pbuf[ot * 256 + (lq * 4 + r) * 16 + l15] = oacc[r];
    }
    __syncthreads();
    if (kh == 0) {
        const int sidx = s0 + l15;
        const bool infs = isinf(sup[(size_t)b * 3 * S_ + sidx]);
        #pragma unroll
        for (int r = 0; r < 4; ++r) {
            const float v = oacc[r] + pbuf[ot * 256 + (lq * 4 + r) * 16 + l15];
            const int o = ot * 16 + lq * 4 + r;
            out[((size_t)b * COUT_ + o) * S_ + sidx] = infs ? INFINITY : v;
        }
    }
}

// ---------------------------------------------------------------------------
extern "C" void kernel_launch(void* const* d_in, const int* in_sizes, int n_in,
                              void* d_out, int out_size, void* d_ws, size_t ws_size,
                              hipStream_t stream)
{
    const float* x   = (const float*)d_in[0];
    const float* pos = (const float*)d_in[1];
    const float* sup = (const float*)d_in[2];
    const int*   nbr = (const int*)d_in[3];
    const float* rad = (const float*)d_in[4];
    const float* w1  = (const float*)d_in[5];
    const float* w2  = (const float*)d_in[6];
    const float* w3  = (const float*)d_in[7];
    const float* wcv = (const float*)d_in[8];
    float* out = (float*)d_out;

    char* p = (char*)d_ws;
    unsigned short* xTB = (unsigned short*)p;  p += (size_t)B_ * N_ * 64 * sizeof(unsigned short);
    float* posT = (float*)p;                   p += (size_t)B_ * N_ * 4 * sizeof(float);
    unsigned short* wcvB = (unsigned short*)p; p += (size_t)COUT_ * 1024 * sizeof(unsigned short);

    prep_kernel<<<dim3(2816), 256, 0, stream>>>(x, xTB, pos, posT, wcv, wcvB);

    fka_fused_kernel<<<dim3(S_ / 16, B_), 512, 0, stream>>>(
        posT, sup, nbr, rad, w1, w2, w3, xTB, wcvB, out);
}

// Round 16
// 74.512 us; speedup vs baseline: 1.2363x; 1.0283x over previous
//
#include <hip/hip_runtime.h>
#include <math.h>

#define B_    4
#define CIN_  64
#define COUT_ 64
#define N_    32768
#define S_    8192

typedef __attribute__((ext_vector_type(8))) short short8;
typedef __attribute__((ext_vector_type(4))) float f32x4a;
typedef _Float16 __attribute__((ext_vector_type(2))) h2v;

static __device__ __forceinline__ unsigned short f2bf(float x) {
    unsigned u = __float_as_uint(x);
    u += 0x7fffu + ((u >> 16) & 1u);
    return (unsigned short)(u >> 16);
}
static __device__ __forceinline__ unsigned pack2bf(float a, float b) {
    return (unsigned)f2bf(a) | ((unsigned)f2bf(b) << 16);
}
// pack two f32 -> fp16 pair (RNE via _Float16 cast)
static __device__ __forceinline__ unsigned packh2(float x, float y) {
    union { h2v v; unsigned u; } c;
    c.v[0] = (_Float16)x; c.v[1] = (_Float16)y;
    return c.u;
}
// packed fp16 max (values are post-ReLU finite -> select == max)
static __device__ __forceinline__ unsigned pkmax2(unsigned a, unsigned b) {
    union { unsigned u; h2v v; } ca, cb, cr;
    ca.u = a; cb.u = b;
    cr.v[0] = ca.v[0] > cb.v[0] ? ca.v[0] : cb.v[0];
    cr.v[1] = ca.v[1] > cb.v[1] ? ca.v[1] : cb.v[1];
    return cr.u;
}
// f32 += dot2(fp16 pair, fp16 pair)  -- v_dot2_f32_f16, f32 accumulate
static __device__ __forceinline__ float fdot2u(unsigned a, unsigned b, float c) {
    union { unsigned u; h2v v; } ca, cb; ca.u = a; cb.u = b;
    return __builtin_amdgcn_fdot2(ca.v, cb.v, c, false);
}
template <int CTRL>
static __device__ __forceinline__ unsigned pmax_ror(unsigned v) {
    unsigned r = (unsigned)__builtin_amdgcn_update_dpp(
        (int)v, (int)v, CTRL, 0xf, 0xf, false);
    return pkmax2(v, r);
}
#define ROR8 0x128
#define ROR4 0x124
#define ROR2 0x122
#define ROR1 0x121

// feats LDS swizzle (r14): row p (2048B rows), col = byte offset within row.
static __device__ __forceinline__ int fl(int p, int col) {
    return p * 2048 + (col ^ ((p & 7) << 4) ^ (((col >> 7) & 7) << 4));
}

// ---------------------------------------------------------------------------
// Merged prep kernel:
//   blocks [0, 2048)    : transpose x [B][64][N] f32 -> xTB [B][N][64] bf16
//   blocks [2048, 2560) : pos [B][3][N] -> posT [B][N][4]
//   blocks [2560, 2816) : wcv f32 [o][c][k] -> wcvB bf16 [o][k*64+c]
//   blocks [2816, 2818) : w2/w3 -> fp16-packed wh[layer][k][16]
//                         (j<8: m-part pairs, j>=8: mp-part pairs)
// ---------------------------------------------------------------------------
__global__ __launch_bounds__(256) void prep_kernel(
    const float* __restrict__ x,   unsigned short* __restrict__ xTB,
    const float* __restrict__ pos, float* __restrict__ posT,
    const float* __restrict__ wcv, unsigned short* __restrict__ wcvB,
    const float* __restrict__ w2,  const float* __restrict__ w3,
    unsigned* __restrict__ wh)
{
    const int bid = blockIdx.x;

    if (bid < 2048) {
        __shared__ float tile[64][65];
        const int b  = bid >> 9;
        const int n0 = (bid & 511) * 64;
        const int tx = threadIdx.x & 63;
        const int ty = threadIdx.x >> 6;

        const float* xb = x + (size_t)b * CIN_ * N_;
        #pragma unroll
        for (int c = ty; c < 64; c += 4)
            tile[c][tx] = xb[(size_t)c * N_ + n0 + tx];
        __syncthreads();

        const int cp = threadIdx.x & 31;
        const int r0 = threadIdx.x >> 5;
        unsigned short* xTb = xTB + ((size_t)b * N_ + n0) * 64;
        #pragma unroll
        for (int nn = r0; nn < 64; nn += 8) {
            ushort2 v;
            v.x = f2bf(tile[2 * cp][nn]);
            v.y = f2bf(tile[2 * cp + 1][nn]);
            *(ushort2*)&xTb[(size_t)nn * 64 + 2 * cp] = v;
        }
    } else if (bid < 2560) {
        const int r = bid - 2048;
        const int b = r >> 7;
        const int n = (r & 127) * 256 + threadIdx.x;
        const float* pb = pos + (size_t)b * 3 * N_;
        float4 v = make_float4(pb[n], pb[N_ + n], pb[2 * N_ + n], 0.0f);
        *(float4*)&posT[((size_t)b * N_ + n) * 4] = v;
    } else if (bid < 2816) {
        const int i = (bid - 2560) * 256 + threadIdx.x;
        const int o   = i >> 10;
        const int rem = i & 1023;
        const int k   = rem >> 6;
        const int c   = rem & 63;
        wcvB[i] = f2bf(wcv[(size_t)o * 1024 + c * 16 + k]);
    } else {
        const int e = (bid - 2816) * 256 + threadIdx.x;   // 0..511
        const int layer = e >> 8, k = (e >> 4) & 15, j = e & 15;
        const float* w = layer ? w3 : w2;
        const int base = (j < 8) ? (2 * j) : (16 + 2 * (j - 8));
        wh[e] = packh2(w[k * 32 + base], w[k * 32 + base + 1]);
    }
}

// ---------------------------------------------------------------------------
// Fused kernel: 512 threads, 16 points (r14 structure; phase 1 on dot2-fp16).
// ---------------------------------------------------------------------------
__global__ __launch_bounds__(512) void fka_fused_kernel(
    const float* __restrict__ posT, const float* __restrict__ sup,
    const int*   __restrict__ nbr, const float* __restrict__ radius,
    const float* __restrict__ w1,  const unsigned* __restrict__ wh,
    const unsigned short* __restrict__ xTB,
    const unsigned short* __restrict__ wcvB,
    float* __restrict__ out)
{
    __shared__ unsigned short featsL[16 * 1024];  // 32KB; head of row p aliases m3 frag
    __shared__ int   idxs[16][32];
    __shared__ float t2s[16][16];
    __shared__ float pbuf[1024];

    const int b  = blockIdx.y;
    const int t  = threadIdx.x;
    const int g  = t >> 5;
    const int n  = t & 31;
    const int s0 = blockIdx.x * 16;
    const int s  = s0 + g;

    // ---- gather + dw ----
    const int raw    = nbr[(((size_t)b * S_ + s) << 5) + n];
    const bool valid = raw > -1;
    const int id     = valid ? raw : 0;

    unsigned long long bal = __ballot(valid);
    unsigned bits = (unsigned)(bal >> (t & 32));
    const float nrm = sqrtf((float)__popc(bits));
    float dw = valid ? (1.0f / fmaxf(nrm, 1e-12f)) : 0.0f;

    const float4 pg = *(const float4*)&posT[((size_t)b * N_ + id) * 4];
    float px = pg.x - sup[(size_t)(b * 3 + 0) * S_ + s];
    float py = pg.y - sup[(size_t)(b * 3 + 1) * S_ + s];
    float pz = pg.z - sup[(size_t)(b * 3 + 2) * S_ + s];
    if (isinf(px)) dw = 0.0f;
    px = (isnan(px) || isinf(px)) ? 0.0f : px;
    py = (isnan(py) || isinf(py)) ? 0.0f : py;
    pz = (isnan(pz) || isinf(pz)) ? 0.0f : pz;
    const float inv_r = 1.0f / radius[0];
    px *= inv_r; py *= inv_r; pz *= inv_r;

    const int kk = n & 15;

    // ---- fc1 (f32 exact) -> packed fp16 m1h ----
    unsigned m1h[8];
    #pragma unroll
    for (int j = 0; j < 8; ++j) {
        float v0 = w1[(2*j) * 3 + 0] * px + w1[(2*j) * 3 + 1] * py + w1[(2*j) * 3 + 2] * pz;
        float v1 = w1[(2*j+1) * 3 + 0] * px + w1[(2*j+1) * 3 + 1] * py + w1[(2*j+1) * 3 + 2] * pz;
        m1h[j] = packh2(fmaxf(v0, 0.0f) * dw, fmaxf(v1, 0.0f) * dw);
    }
    // ---- mp1 (packed fp16 max over 32 lanes) ----
    unsigned mp1h[8];
    #pragma unroll
    for (int j = 0; j < 8; ++j) {
        unsigned v = m1h[j];
        v = pkmax2(v, (unsigned)__shfl_xor((int)v, 16, 32));
        v = pmax_ror<ROR8>(v); v = pmax_ror<ROR4>(v);
        v = pmax_ror<ROR2>(v); v = pmax_ror<ROR1>(v);
        mp1h[j] = v;
    }
    // ---- t2 cooperative bias (fdot2, f32 accumulate) ----
    {
        const unsigned* wp = wh + kk * 16 + 8;
        float pa = 0.0f, pb = 0.0f;
        #pragma unroll
        for (int j = 0; j < 4; ++j) pa = fdot2u(wp[j], mp1h[j], pa);
        #pragma unroll
        for (int j = 0; j < 4; ++j) pb = fdot2u(wp[4 + j], mp1h[4 + j], pb);
        float tp = (n & 16) ? pb : pa;
        tp += __shfl_xor(tp, 16, 32);
        t2s[g][kk] = tp;
    }
    // ---- fc2 m-part (fdot2, uniform weight rows) -> m2h ----
    unsigned m2h[8];
    {
        float4 ta = *(const float4*)&t2s[g][0];
        float4 tb = *(const float4*)&t2s[g][4];
        float4 tc = *(const float4*)&t2s[g][8];
        float4 td = *(const float4*)&t2s[g][12];
        float t2v[16] = {ta.x, ta.y, ta.z, ta.w, tb.x, tb.y, tb.z, tb.w,
                         tc.x, tc.y, tc.z, tc.w, td.x, td.y, td.z, td.w};
        float m2[16];
        #pragma unroll
        for (int k = 0; k < 16; ++k) {
            const unsigned* wm = wh + k * 16;
            float v = t2v[k];
            #pragma unroll
            for (int j = 0; j < 8; ++j) v = fdot2u(wm[j], m1h[j], v);
            m2[k] = fmaxf(v, 0.0f) * dw;
        }
        #pragma unroll
        for (int j = 0; j < 8; ++j) m2h[j] = packh2(m2[2*j], m2[2*j+1]);
    }
    // ---- mp2 ----
    unsigned mp2h[8];
    #pragma unroll
    for (int j = 0; j < 8; ++j) {
        unsigned v = m2h[j];
        v = pkmax2(v, (unsigned)__shfl_xor((int)v, 16, 32));
        v = pmax_ror<ROR8>(v); v = pmax_ror<ROR4>(v);
        v = pmax_ror<ROR2>(v); v = pmax_ror<ROR1>(v);
        mp2h[j] = v;
    }
    // ---- t3 cooperative bias ----
    {
        const unsigned* wp = wh + 256 + kk * 16 + 8;
        float pa = 0.0f, pb = 0.0f;
        #pragma unroll
        for (int j = 0; j < 4; ++j) pa = fdot2u(wp[j], mp2h[j], pa);
        #pragma unroll
        for (int j = 0; j < 4; ++j) pb = fdot2u(wp[4 + j], mp2h[4 + j], pb);
        float tp = (n & 16) ? pb : pa;
        tp += __shfl_xor(tp, 16, 32);
        t2s[g][kk] = tp;
    }
    // ---- fc3 m-part -> m3 (f32) -> bf16 frag ----
    float m3[16];
    {
        float4 ta = *(const float4*)&t2s[g][0];
        float4 tb = *(const float4*)&t2s[g][4];
        float4 tc = *(const float4*)&t2s[g][8];
        float4 td = *(const float4*)&t2s[g][12];
        float t3v[16] = {ta.x, ta.y, ta.z, ta.w, tb.x, tb.y, tb.z, tb.w,
                         tc.x, tc.y, tc.z, tc.w, td.x, td.y, td.z, td.w};
        #pragma unroll
        for (int k = 0; k < 16; ++k) {
            const unsigned* wm = wh + 256 + k * 16;
            float v = t3v[k];
            #pragma unroll
            for (int j = 0; j < 8; ++j) v = fdot2u(wm[j], m2h[j], v);
            m3[k] = fmaxf(v, 0.0f) * dw;
        }
    }

    idxs[g][n] = id;
    {
        const int hi = n >> 3, jj = n & 7;
        unsigned short* base = &featsL[g * 1024 + hi * 128 + jj];
        #pragma unroll
        for (int k = 0; k < 16; ++k) {
            const int row = (k + hi + g) & 15;
            base[row * 8] = f2bf(m3[k]);
        }
    }
    // wave-local -> no barrier before phase 2

    // ---- phase 2: feats via MFMA (2 points per wave) -> swizzled LDS ----
    const int wv  = t >> 6;
    const int l   = t & 63;
    const int hi2 = l >> 4;
    const int k15 = l & 15;
    const unsigned short* xb = xTB + (size_t)b * N_ * 64;
    char* fLp = (char*)featsL;

    short8 bfrag[2];
    #pragma unroll
    for (int pp = 0; pp < 2; ++pp) {
        const int p = wv * 2 + pp;
        const int brow = (k15 + hi2 + p) & 15;
        bfrag[pp] = *(const short8*)&featsL[p * 1024 + hi2 * 128 + brow * 8];
    }

    #pragma unroll
    for (int pp = 0; pp < 2; ++pp) {
        const int p = wv * 2 + pp;

        int ids8[8];
        #pragma unroll
        for (int j = 0; j < 8; ++j) ids8[j] = idxs[p][hi2 * 8 + j];

        f32x4a acc[4];
        #pragma unroll
        for (int ct = 0; ct < 4; ++ct) acc[ct] = (f32x4a){0.f, 0.f, 0.f, 0.f};

        #pragma unroll
        for (int ct = 0; ct < 4; ++ct) {
            union { unsigned short u[8]; short8 v; } A;
            #pragma unroll
            for (int j = 0; j < 8; ++j)
                A.u[j] = xb[((size_t)ids8[j] << 6) + ct * 16 + k15];
            acc[ct] = __builtin_amdgcn_mfma_f32_16x16x32_bf16(A.v, bfrag[pp], acc[ct], 0, 0, 0);
        }

        #pragma unroll
        for (int ct = 0; ct < 4; ++ct) {
            uint2 val;
            val.x = pack2bf(acc[ct][0], acc[ct][1]);
            val.y = pack2bf(acc[ct][2], acc[ct][3]);
            const int col = k15 * 128 + ct * 32 + hi2 * 8;
            *(uint2*)(fLp + fl(p, col)) = val;
        }
    }
    __syncthreads();

    // ---- phase 3: out tile 64 x 16 ----
    const int ot  = wv & 3;
    const int kh  = wv >> 2;
    const int lq  = hi2;
    const int l15 = k15;

    const unsigned short* apod =
        wcvB + (size_t)(ot * 16 + l15) * 1024 + kh * 512 + lq * 8;

    f32x4a oacc = (f32x4a){0.f, 0.f, 0.f, 0.f};
    #pragma unroll 4
    for (int ks = 0; ks < 16; ++ks) {
        const int col = kh * 1024 + ks * 64 + lq * 16;
        short8 bfv = *(const short8*)(fLp + fl(l15, col));
        short8 afv = *(const short8*)(apod + ks * 32);
        oacc = __builtin_amdgcn_mfma_f32_16x16x32_bf16(afv, bfv, oacc, 0, 0, 0);
    }

    if (kh == 1) {
        #pragma unroll
        for (int r = 0; r < 4; ++r)
            pbuf[ot * 256 + (lq * 4 + r) * 16 + l15] = oacc[r];
    }
    __syncthreads();
    if (kh == 0) {
        const int sidx = s0 + l15;
        const bool infs = isinf(sup[(size_t)b * 3 * S_ + sidx]);
        #pragma unroll
        for (int r = 0; r < 4; ++r) {
            const float v = oacc[r] + pbuf[ot * 256 + (lq * 4 + r) * 16 + l15];
            const int o = ot * 16 + lq * 4 + r;
            out[((size_t)b * COUT_ + o) * S_ + sidx] = infs ? INFINITY : v;
        }
    }
}

// ---------------------------------------------------------------------------
extern "C" void kernel_launch(void* const* d_in, const int* in_sizes, int n_in,
                              void* d_out, int out_size, void* d_ws, size_t ws_size,
                              hipStream_t stream)
{
    const float* x   = (const float*)d_in[0];
    const float* pos = (const float*)d_in[1];
    const float* sup = (const float*)d_in[2];
    const int*   nbr = (const int*)d_in[3];
    const float* rad = (const float*)d_in[4];
    const float* w1  = (const float*)d_in[5];
    const float* w2  = (const float*)d_in[6];
    const float* w3  = (const float*)d_in[7];
    const float* wcv = (const float*)d_in[8];
    float* out = (float*)d_out;

    char* p = (char*)d_ws;
    unsigned short* xTB = (unsigned short*)p;  p += (size_t)B_ * N_ * 64 * sizeof(unsigned short);
    float* posT = (float*)p;                   p += (size_t)B_ * N_ * 4 * sizeof(float);
    unsigned short* wcvB = (unsigned short*)p; p += (size_t)COUT_ * 1024 * sizeof(unsigned short);
    unsigned* wh = (unsigned*)p;               p += (size_t)512 * sizeof(unsigned);

    prep_kernel<<<dim3(2818), 256, 0, stream>>>(x, xTB, pos, posT, wcv, wcvB, w2, w3, wh);

    fka_fused_kernel<<<dim3(S_ / 16, B_), 512, 0, stream>>>(
        posT, sup, nbr, rad, w1, wh, xTB, wcvB, out);
}

// Round 17
// 69.666 us; speedup vs baseline: 1.3222x; 1.0696x over previous
//
#include <hip/hip_runtime.h>
#include <math.h>

#define B_    4
#define CIN_  64
#define COUT_ 64
#define N_    32768
#define S_    8192

typedef __attribute__((ext_vector_type(8))) short short8;
typedef __attribute__((ext_vector_type(4))) float f32x4a;
typedef _Float16 __attribute__((ext_vector_type(2))) h2v;

static __device__ __forceinline__ unsigned short f2bf(float x) {
    unsigned u = __float_as_uint(x);
    u += 0x7fffu + ((u >> 16) & 1u);
    return (unsigned short)(u >> 16);
}
static __device__ __forceinline__ unsigned pack2bf(float a, float b) {
    return (unsigned)f2bf(a) | ((unsigned)f2bf(b) << 16);
}
// pack two f32 -> fp16 pair (RNE via _Float16 cast)
static __device__ __forceinline__ unsigned packh2(float x, float y) {
    union { h2v v; unsigned u; } c;
    c.v[0] = (_Float16)x; c.v[1] = (_Float16)y;
    return c.u;
}
// packed fp16 max (values are post-ReLU finite -> select == max)
static __device__ __forceinline__ unsigned pkmax2(unsigned a, unsigned b) {
    union { unsigned u; h2v v; } ca, cb, cr;
    ca.u = a; cb.u = b;
    cr.v[0] = ca.v[0] > cb.v[0] ? ca.v[0] : cb.v[0];
    cr.v[1] = ca.v[1] > cb.v[1] ? ca.v[1] : cb.v[1];
    return cr.u;
}
// packed ReLU + scale: max(v,0) * dw, all fp16
static __device__ __forceinline__ unsigned pkrelu_mul(unsigned v, unsigned dwp) {
    union { unsigned u; h2v v; } a, d, r;
    a.u = v; d.u = dwp;
    const _Float16 z = (_Float16)0.f;
    r.v[0] = (a.v[0] > z ? a.v[0] : z) * d.v[0];
    r.v[1] = (a.v[1] > z ? a.v[1] : z) * d.v[1];
    return r.u;
}
// f32 += dot2(fp16 pair, fp16 pair)  -- v_dot2_f32_f16, f32 accumulate
static __device__ __forceinline__ float fdot2u(unsigned a, unsigned b, float c) {
    union { unsigned u; h2v v; } ca, cb; ca.u = a; cb.u = b;
    return __builtin_amdgcn_fdot2(ca.v, cb.v, c, false);
}
template <int CTRL>
static __device__ __forceinline__ unsigned pmax_ror(unsigned v) {
    unsigned r = (unsigned)__builtin_amdgcn_update_dpp(
        (int)v, (int)v, CTRL, 0xf, 0xf, false);
    return pkmax2(v, r);
}
#define ROR8 0x128
#define ROR4 0x124
#define ROR2 0x122
#define ROR1 0x121

// feats LDS swizzle (r14): row p (2048B rows), col = byte offset within row.
static __device__ __forceinline__ int fl(int p, int col) {
    return p * 2048 + (col ^ ((p & 7) << 4) ^ (((col >> 7) & 7) << 4));
}

// ---------------------------------------------------------------------------
// Merged prep kernel:
//   blocks [0, 2048)    : transpose x -> xTB [B][N][64] bf16, channel pos
//                         interleaved: pos(c) = (c&15)*4 + (c>>4)
//   blocks [2048, 2560) : pos [B][3][N] -> posT [B][N][4]
//   blocks [2560, 2816) : wcv f32 [o][c][k] -> wcvB bf16 [o][k*64+c]
//   blocks [2816, 2818) : w2/w3 -> fp16-packed wh[layer][k][16]
// ---------------------------------------------------------------------------
__global__ __launch_bounds__(256) void prep_kernel(
    const float* __restrict__ x,   unsigned short* __restrict__ xTB,
    const float* __restrict__ pos, float* __restrict__ posT,
    const float* __restrict__ wcv, unsigned short* __restrict__ wcvB,
    const float* __restrict__ w2,  const float* __restrict__ w3,
    unsigned* __restrict__ wh)
{
    const int bid = blockIdx.x;

    if (bid < 2048) {
        __shared__ float tile[64][65];
        const int b  = bid >> 9;
        const int n0 = (bid & 511) * 64;
        const int tx = threadIdx.x & 63;
        const int ty = threadIdx.x >> 6;

        const float* xb = x + (size_t)b * CIN_ * N_;
        #pragma unroll
        for (int c = ty; c < 64; c += 4)
            tile[c][tx] = xb[(size_t)c * N_ + n0 + tx];
        __syncthreads();

        // lane (k15p, rg): writes channels {k15p, 16+k15p, 32+k15p, 48+k15p}
        // of rows rg+16q as one contiguous uint2 at ushort offset k15p*4
        const int k15p = threadIdx.x & 15;
        const int rg   = threadIdx.x >> 4;     // 0..15
        unsigned short* xTb = xTB + ((size_t)b * N_ + n0) * 64;
        #pragma unroll
        for (int q = 0; q < 4; ++q) {
            const int nn = rg + q * 16;
            union { uint2 u; unsigned short us[4]; } v;
            v.us[0] = f2bf(tile[k15p][nn]);
            v.us[1] = f2bf(tile[16 + k15p][nn]);
            v.us[2] = f2bf(tile[32 + k15p][nn]);
            v.us[3] = f2bf(tile[48 + k15p][nn]);
            *(uint2*)&xTb[(size_t)nn * 64 + k15p * 4] = v.u;
        }
    } else if (bid < 2560) {
        const int r = bid - 2048;
        const int b = r >> 7;
        const int n = (r & 127) * 256 + threadIdx.x;
        const float* pb = pos + (size_t)b * 3 * N_;
        float4 v = make_float4(pb[n], pb[N_ + n], pb[2 * N_ + n], 0.0f);
        *(float4*)&posT[((size_t)b * N_ + n) * 4] = v;
    } else if (bid < 2816) {
        const int i = (bid - 2560) * 256 + threadIdx.x;
        const int o   = i >> 10;
        const int rem = i & 1023;
        const int k   = rem >> 6;
        const int c   = rem & 63;
        wcvB[i] = f2bf(wcv[(size_t)o * 1024 + c * 16 + k]);
    } else {
        const int e = (bid - 2816) * 256 + threadIdx.x;   // 0..511
        const int layer = e >> 8, k = (e >> 4) & 15, j = e & 15;
        const float* w = layer ? w3 : w2;
        const int base = (j < 8) ? (2 * j) : (16 + 2 * (j - 8));
        wh[e] = packh2(w[k * 32 + base], w[k * 32 + base + 1]);
    }
}

// ---------------------------------------------------------------------------
// Fused kernel: 512 threads, 16 points (r16 structure; dwordx2 gathers +
// packed fp16 fc epilogues).
// ---------------------------------------------------------------------------
__global__ __launch_bounds__(512) void fka_fused_kernel(
    const float* __restrict__ posT, const float* __restrict__ sup,
    const int*   __restrict__ nbr, const float* __restrict__ radius,
    const float* __restrict__ w1,  const unsigned* __restrict__ wh,
    const unsigned short* __restrict__ xTB,
    const unsigned short* __restrict__ wcvB,
    float* __restrict__ out)
{
    __shared__ unsigned short featsL[16 * 1024];  // 32KB; head of row p aliases m3 frag
    __shared__ int   idxs[16][32];
    __shared__ float t2s[16][16];
    __shared__ float pbuf[1024];

    const int b  = blockIdx.y;
    const int t  = threadIdx.x;
    const int g  = t >> 5;
    const int n  = t & 31;
    const int s0 = blockIdx.x * 16;
    const int s  = s0 + g;

    // ---- gather + dw ----
    const int raw    = nbr[(((size_t)b * S_ + s) << 5) + n];
    const bool valid = raw > -1;
    const int id     = valid ? raw : 0;

    unsigned long long bal = __ballot(valid);
    unsigned bits = (unsigned)(bal >> (t & 32));
    const float nrm = sqrtf((float)__popc(bits));
    float dw = valid ? (1.0f / fmaxf(nrm, 1e-12f)) : 0.0f;

    const float4 pg = *(const float4*)&posT[((size_t)b * N_ + id) * 4];
    float px = pg.x - sup[(size_t)(b * 3 + 0) * S_ + s];
    float py = pg.y - sup[(size_t)(b * 3 + 1) * S_ + s];
    float pz = pg.z - sup[(size_t)(b * 3 + 2) * S_ + s];
    if (isinf(px)) dw = 0.0f;
    px = (isnan(px) || isinf(px)) ? 0.0f : px;
    py = (isnan(py) || isinf(py)) ? 0.0f : py;
    pz = (isnan(pz) || isinf(pz)) ? 0.0f : pz;
    const float inv_r = 1.0f / radius[0];
    px *= inv_r; py *= inv_r; pz *= inv_r;

    const int kk = n & 15;
    const unsigned dwh2 = packh2(dw, dw);

    // ---- fc1 (f32 fma) -> packed fp16 epilogue ----
    unsigned m1h[8];
    #pragma unroll
    for (int j = 0; j < 8; ++j) {
        float v0 = w1[(2*j) * 3 + 0] * px + w1[(2*j) * 3 + 1] * py + w1[(2*j) * 3 + 2] * pz;
        float v1 = w1[(2*j+1) * 3 + 0] * px + w1[(2*j+1) * 3 + 1] * py + w1[(2*j+1) * 3 + 2] * pz;
        m1h[j] = pkrelu_mul(packh2(v0, v1), dwh2);
    }
    // ---- mp1 (packed fp16 max over 32 lanes) ----
    unsigned mp1h[8];
    #pragma unroll
    for (int j = 0; j < 8; ++j) {
        unsigned v = m1h[j];
        v = pkmax2(v, (unsigned)__shfl_xor((int)v, 16, 32));
        v = pmax_ror<ROR8>(v); v = pmax_ror<ROR4>(v);
        v = pmax_ror<ROR2>(v); v = pmax_ror<ROR1>(v);
        mp1h[j] = v;
    }
    // ---- t2 cooperative bias (fdot2, f32 accumulate) ----
    {
        const unsigned* wp = wh + kk * 16 + 8;
        float pa = 0.0f, pb = 0.0f;
        #pragma unroll
        for (int j = 0; j < 4; ++j) pa = fdot2u(wp[j], mp1h[j], pa);
        #pragma unroll
        for (int j = 0; j < 4; ++j) pb = fdot2u(wp[4 + j], mp1h[4 + j], pb);
        float tp = (n & 16) ? pb : pa;
        tp += __shfl_xor(tp, 16, 32);
        t2s[g][kk] = tp;
    }
    // ---- fc2 m-part (fdot2) -> packed epilogue -> m2h ----
    unsigned m2h[8];
    {
        float4 ta = *(const float4*)&t2s[g][0];
        float4 tb = *(const float4*)&t2s[g][4];
        float4 tc = *(const float4*)&t2s[g][8];
        float4 td = *(const float4*)&t2s[g][12];
        float t2v[16] = {ta.x, ta.y, ta.z, ta.w, tb.x, tb.y, tb.z, tb.w,
                         tc.x, tc.y, tc.z, tc.w, td.x, td.y, td.z, td.w};
        #pragma unroll
        for (int j = 0; j < 8; ++j) {
            const unsigned* wmA = wh + (2*j) * 16;
            const unsigned* wmB = wh + (2*j+1) * 16;
            float vA = t2v[2*j], vB = t2v[2*j+1];
            #pragma unroll
            for (int q = 0; q < 8; ++q) {
                vA = fdot2u(wmA[q], m1h[q], vA);
                vB = fdot2u(wmB[q], m1h[q], vB);
            }
            m2h[j] = pkrelu_mul(packh2(vA, vB), dwh2);
        }
    }
    // ---- mp2 ----
    unsigned mp2h[8];
    #pragma unroll
    for (int j = 0; j < 8; ++j) {
        unsigned v = m2h[j];
        v = pkmax2(v, (unsigned)__shfl_xor((int)v, 16, 32));
        v = pmax_ror<ROR8>(v); v = pmax_ror<ROR4>(v);
        v = pmax_ror<ROR2>(v); v = pmax_ror<ROR1>(v);
        mp2h[j] = v;
    }
    // ---- t3 cooperative bias ----
    {
        const unsigned* wp = wh + 256 + kk * 16 + 8;
        float pa = 0.0f, pb = 0.0f;
        #pragma unroll
        for (int j = 0; j < 4; ++j) pa = fdot2u(wp[j], mp2h[j], pa);
        #pragma unroll
        for (int j = 0; j < 4; ++j) pb = fdot2u(wp[4 + j], mp2h[4 + j], pb);
        float tp = (n & 16) ? pb : pa;
        tp += __shfl_xor(tp, 16, 32);
        t2s[g][kk] = tp;
    }
    // ---- fc3 m-part -> m3 (f32) -> bf16 frag ----
    float m3[16];
    {
        float4 ta = *(const float4*)&t2s[g][0];
        float4 tb = *(const float4*)&t2s[g][4];
        float4 tc = *(const float4*)&t2s[g][8];
        float4 td = *(const float4*)&t2s[g][12];
        float t3v[16] = {ta.x, ta.y, ta.z, ta.w, tb.x, tb.y, tb.z, tb.w,
                         tc.x, tc.y, tc.z, tc.w, td.x, td.y, td.z, td.w};
        #pragma unroll
        for (int k = 0; k < 16; ++k) {
            const unsigned* wm = wh + 256 + k * 16;
            float v = t3v[k];
            #pragma unroll
            for (int j = 0; j < 8; ++j) v = fdot2u(wm[j], m2h[j], v);
            m3[k] = fmaxf(v, 0.0f) * dw;
        }
    }

    idxs[g][n] = id;
    {
        const int hi = n >> 3, jj = n & 7;
        unsigned short* base = &featsL[g * 1024 + hi * 128 + jj];
        #pragma unroll
        for (int k = 0; k < 16; ++k) {
            const int row = (k + hi + g) & 15;
            base[row * 8] = f2bf(m3[k]);
        }
    }
    // wave-local -> no barrier before phase 2

    // ---- phase 2: feats via MFMA (2 points per wave) -> swizzled LDS ----
    const int wv  = t >> 6;
    const int l   = t & 63;
    const int hi2 = l >> 4;
    const int k15 = l & 15;
    const unsigned short* xb = xTB + (size_t)b * N_ * 64;
    char* fLp = (char*)featsL;

    short8 bfrag[2];
    #pragma unroll
    for (int pp = 0; pp < 2; ++pp) {
        const int p = wv * 2 + pp;
        const int brow = (k15 + hi2 + p) & 15;
        bfrag[pp] = *(const short8*)&featsL[p * 1024 + hi2 * 128 + brow * 8];
    }

    #pragma unroll
    for (int pp = 0; pp < 2; ++pp) {
        const int p = wv * 2 + pp;

        int ids8[8];
        #pragma unroll
        for (int j = 0; j < 8; ++j) ids8[j] = idxs[p][hi2 * 8 + j];

        // one dwordx2 per neighbor: channels {k15, 16+k15, 32+k15, 48+k15}
        union { uint2 q; unsigned short us[4]; } xq[8];
        #pragma unroll
        for (int j = 0; j < 8; ++j)
            xq[j].q = *(const uint2*)(xb + ((size_t)ids8[j] << 6) + (k15 << 2));

        f32x4a acc[4];
        #pragma unroll
        for (int ct = 0; ct < 4; ++ct) acc[ct] = (f32x4a){0.f, 0.f, 0.f, 0.f};

        #pragma unroll
        for (int ct = 0; ct < 4; ++ct) {
            union { unsigned short u[8]; short8 v; } A;
            #pragma unroll
            for (int j = 0; j < 8; ++j) A.u[j] = xq[j].us[ct];
            acc[ct] = __builtin_amdgcn_mfma_f32_16x16x32_bf16(A.v, bfrag[pp], acc[ct], 0, 0, 0);
        }

        #pragma unroll
        for (int ct = 0; ct < 4; ++ct) {
            uint2 val;
            val.x = pack2bf(acc[ct][0], acc[ct][1]);
            val.y = pack2bf(acc[ct][2], acc[ct][3]);
            const int col = k15 * 128 + ct * 32 + hi2 * 8;
            *(uint2*)(fLp + fl(p, col)) = val;
        }
    }
    __syncthreads();

    // ---- phase 3: out tile 64 x 16 ----
    const int ot  = wv & 3;
    const int kh  = wv >> 2;
    const int lq  = hi2;
    const int l15 = k15;

    const unsigned short* apod =
        wcvB + (size_t)(ot * 16 + l15) * 1024 + kh * 512 + lq * 8;

    f32x4a oacc = (f32x4a){0.f, 0.f, 0.f, 0.f};
    #pragma unroll 4
    for (int ks = 0; ks < 16; ++ks) {
        const int col = kh * 1024 + ks * 64 + lq * 16;
        short8 bfv = *(const short8*)(fLp + fl(l15, col));
        short8 afv = *(const short8*)(apod + ks * 32);
        oacc = __builtin_amdgcn_mfma_f32_16x16x32_bf16(afv, bfv, oacc, 0, 0, 0);
    }

    if (kh == 1) {
        #pragma unroll
        for (int r = 0; r < 4; ++r)
            pbuf[ot * 256 + (lq * 4 + r) * 16 + l15] = oacc[r];
    }
    __syncthreads();
    if (kh == 0) {
        const int sidx = s0 + l15;
        const bool infs = isinf(sup[(size_t)b * 3 * S_ + sidx]);
        #pragma unroll
        for (int r = 0; r < 4; ++r) {
            const float v = oacc[r] + pbuf[ot * 256 + (lq * 4 + r) * 16 + l15];
            const int o = ot * 16 + lq * 4 + r;
            out[((size_t)b * COUT_ + o) * S_ + sidx] = infs ? INFINITY : v;
        }
    }
}

// ---------------------------------------------------------------------------
extern "C" void kernel_launch(void* const* d_in, const int* in_sizes, int n_in,
                              void* d_out, int out_size, void* d_ws, size_t ws_size,
                              hipStream_t stream)
{
    const float* x   = (const float*)d_in[0];
    const float* pos = (const float*)d_in[1];
    const float* sup = (const float*)d_in[2];
    const int*   nbr = (const int*)d_in[3];
    const float* rad = (const float*)d_in[4];
    const float* w1  = (const float*)d_in[5];
    const float* w2  = (const float*)d_in[6];
    const float* w3  = (const float*)d_in[7];
    const float* wcv = (const float*)d_in[8];
    float* out = (float*)d_out;

    char* p = (char*)d_ws;
    unsigned short* xTB = (unsigned short*)p;  p += (size_t)B_ * N_ * 64 * sizeof(unsigned short);
    float* posT = (float*)p;                   p += (size_t)B_ * N_ * 4 * sizeof(float);
    unsigned short* wcvB = (unsigned short*)p; p += (size_t)COUT_ * 1024 * sizeof(unsigned short);
    unsigned* wh = (unsigned*)p;               p += (size_t)512 * sizeof(unsigned);

    prep_kernel<<<dim3(2818), 256, 0, stream>>>(x, xTB, pos, posT, wcv, wcvB, w2, w3, wh);

    fka_fused_kernel<<<dim3(S_ / 16, B_), 512, 0, stream>>>(
        posT, sup, nbr, rad, w1, wh, xTB, wcvB, out);
}